// Round 2
// baseline (1383.486 us; speedup 1.0000x reference)
//
#include <hip/hip_runtime.h>

#define NN 50000
#define TT 10
#define EE 1000000

__device__ __forceinline__ float sigmoidf_(float v) { return 1.0f / (1.0f + __expf(-v)); }
__device__ __forceinline__ float reluf_(float v) { return v > 0.0f ? v : 0.0f; }

// MLP1: feat[9] -> relu(9x32) -> relu(32x32) -> sigmoid(32x1)
__device__ __forceinline__ float mlp1_eval(const float* feat,
                                           const float* s_w1, const float* s_b1,
                                           const float* s_w2, const float* s_b2,
                                           const float* s_w3, float s_b3) {
    float h1[32];
#pragma unroll
    for (int j = 0; j < 32; ++j) {
        float acc = s_b1[j];
#pragma unroll
        for (int i = 0; i < 9; ++i) acc += feat[i] * s_w1[i * 32 + j];
        h1[j] = reluf_(acc);
    }
    float acc3 = s_b3;
#pragma unroll
    for (int j2 = 0; j2 < 32; ++j2) {
        float acc = s_b2[j2];
#pragma unroll
        for (int i = 0; i < 32; ++i) acc += h1[i] * s_w2[i * 32 + j2];
        acc3 += reluf_(acc) * s_w3[j2];
    }
    return sigmoidf_(acc3);
}

// Init: hidden = 0, agg = 0, msg_base for frame 0 (hidden = 0)
__global__ void init_kernel(const float* __restrict__ x,
                            const float* __restrict__ w1, const float* __restrict__ b1,
                            const float* __restrict__ w2, const float* __restrict__ b2,
                            const float* __restrict__ w3, const float* __restrict__ b3,
                            float* __restrict__ hidden, float* __restrict__ msg_base,
                            float* __restrict__ agg) {
    __shared__ float s_w1[288], s_b1[32], s_w2[1024], s_b2[32], s_w3[32];
    __shared__ float s_b3;
    for (int i = threadIdx.x; i < 288; i += blockDim.x) s_w1[i] = w1[i];
    for (int i = threadIdx.x; i < 1024; i += blockDim.x) s_w2[i] = w2[i];
    if (threadIdx.x < 32) {
        s_b1[threadIdx.x] = b1[threadIdx.x];
        s_b2[threadIdx.x] = b2[threadIdx.x];
        s_w3[threadIdx.x] = w3[threadIdx.x];
    }
    if (threadIdx.x == 0) s_b3 = b3[0];
    __syncthreads();

    int n = blockIdx.x * blockDim.x + threadIdx.x;
    if (n >= NN) return;
    float feat[9];
    feat[0] = x[n * TT * 2 + 0];
#pragma unroll
    for (int k = 0; k < 8; ++k) feat[1 + k] = 0.0f;
    msg_base[n] = mlp1_eval(feat, s_w1, s_b1, s_w2, s_b2, s_w3, s_b3);
    agg[n] = 0.0f;
#pragma unroll
    for (int k = 0; k < 8; ++k) hidden[n * 8 + k] = 0.0f;
}

// Edge scatter: agg[dst] += msg_base[src] * ea[e]; 4 edges per thread
__global__ void edge_kernel(const int* __restrict__ ei, const float* __restrict__ ea,
                            const float* __restrict__ msg_base, float* __restrict__ agg,
                            int t) {
    int g = blockIdx.x * blockDim.x + threadIdx.x;
    int e0 = g * 4;
    if (e0 >= EE) return;
    const int4 srcs = *reinterpret_cast<const int4*>(ei + (size_t)t * EE + e0);
    const int4 dsts = *reinterpret_cast<const int4*>(ei + (size_t)TT * EE + (size_t)t * EE + e0);
    float m0 = msg_base[srcs.x] * ea[(size_t)(e0 + 0) * TT + t];
    float m1 = msg_base[srcs.y] * ea[(size_t)(e0 + 1) * TT + t];
    float m2 = msg_base[srcs.z] * ea[(size_t)(e0 + 2) * TT + t];
    float m3 = msg_base[srcs.w] * ea[(size_t)(e0 + 3) * TT + t];
    atomicAdd(&agg[dsts.x], m0);
    atomicAdd(&agg[dsts.y], m1);
    atomicAdd(&agg[dsts.z], m2);
    atomicAdd(&agg[dsts.w], m3);
}

// Node update for frame t: MLP2 -> tanh -> hidden; h2o -> out[t];
// then msg_base for frame t+1 and agg reset.
__global__ void node_kernel(const float* __restrict__ x,
                            const float* __restrict__ m1w1, const float* __restrict__ m1b1,
                            const float* __restrict__ m1w2, const float* __restrict__ m1b2,
                            const float* __restrict__ m1w3, const float* __restrict__ m1b3,
                            const float* __restrict__ m2w1, const float* __restrict__ m2b1,
                            const float* __restrict__ m2w2, const float* __restrict__ m2b2,
                            const float* __restrict__ ow1, const float* __restrict__ ob1,
                            const float* __restrict__ ow2, const float* __restrict__ ob2,
                            float* __restrict__ hidden, float* __restrict__ msg_base,
                            float* __restrict__ agg, float* __restrict__ out, int t) {
    __shared__ float s_m2w1[320], s_m2b1[32], s_m2w2[256], s_m2b2[8];
    __shared__ float s_ow1[128], s_ob1[16], s_ow2[16];
    __shared__ float s_ob2;
    __shared__ float s_w1[288], s_b1[32], s_w2[1024], s_b2[32], s_w3[32];
    __shared__ float s_b3;

    for (int i = threadIdx.x; i < 320; i += blockDim.x) s_m2w1[i] = m2w1[i];
    for (int i = threadIdx.x; i < 256; i += blockDim.x) s_m2w2[i] = m2w2[i];
    for (int i = threadIdx.x; i < 288; i += blockDim.x) s_w1[i] = m1w1[i];
    for (int i = threadIdx.x; i < 1024; i += blockDim.x) s_w2[i] = m1w2[i];
    for (int i = threadIdx.x; i < 128; i += blockDim.x) s_ow1[i] = ow1[i];
    if (threadIdx.x < 32) {
        s_m2b1[threadIdx.x] = m2b1[threadIdx.x];
        s_b1[threadIdx.x] = m1b1[threadIdx.x];
        s_b2[threadIdx.x] = m1b2[threadIdx.x];
        s_w3[threadIdx.x] = m1w3[threadIdx.x];
    }
    if (threadIdx.x < 16) {
        s_ob1[threadIdx.x] = ob1[threadIdx.x];
        s_ow2[threadIdx.x] = ow2[threadIdx.x];
    }
    if (threadIdx.x < 8) s_m2b2[threadIdx.x] = m2b2[threadIdx.x];
    if (threadIdx.x == 0) { s_ob2 = ob2[0]; s_b3 = m1b3[0]; }
    __syncthreads();

    int n = blockIdx.x * blockDim.x + threadIdx.x;
    if (n >= NN) return;

    float hid[8];
#pragma unroll
    for (int k = 0; k < 8; ++k) hid[k] = hidden[n * 8 + k];
    float x1 = x[n * TT * 2 + t * 2 + 1];
    float a = agg[n];

    float uin[10];
    uin[0] = x1;
#pragma unroll
    for (int k = 0; k < 8; ++k) uin[1 + k] = hid[k];
    uin[9] = a;

    float u1[32];
#pragma unroll
    for (int j = 0; j < 32; ++j) {
        float acc = s_m2b1[j];
#pragma unroll
        for (int i = 0; i < 10; ++i) acc += uin[i] * s_m2w1[i * 32 + j];
        u1[j] = reluf_(acc);
    }
    float hn[8];
#pragma unroll
    for (int k = 0; k < 8; ++k) {
        float acc = s_m2b2[k];
#pragma unroll
        for (int j = 0; j < 32; ++j) acc += u1[j] * s_m2w2[j * 8 + k];
        hn[k] = tanhf(reluf_(acc));
    }
#pragma unroll
    for (int k = 0; k < 8; ++k) hidden[n * 8 + k] = hn[k];

    float o1[16];
#pragma unroll
    for (int l = 0; l < 16; ++l) {
        float acc = s_ob1[l];
#pragma unroll
        for (int k = 0; k < 8; ++k) acc += hn[k] * s_ow1[k * 16 + l];
        o1[l] = reluf_(acc);
    }
    float oo = s_ob2;
#pragma unroll
    for (int l = 0; l < 16; ++l) oo += o1[l] * s_ow2[l];
    out[t * NN + n] = sigmoidf_(oo);

    if (t < TT - 1) {
        float feat[9];
        feat[0] = x[n * TT * 2 + (t + 1) * 2 + 0];
#pragma unroll
        for (int k = 0; k < 8; ++k) feat[1 + k] = hn[k];
        msg_base[n] = mlp1_eval(feat, s_w1, s_b1, s_w2, s_b2, s_w3, s_b3);
        agg[n] = 0.0f;
    }
}

extern "C" void kernel_launch(void* const* d_in, const int* in_sizes, int n_in,
                              void* d_out, int out_size, void* d_ws, size_t ws_size,
                              hipStream_t stream) {
    (void)in_sizes; (void)n_in; (void)out_size; (void)ws_size;
    const float* x    = (const float*)d_in[0];
    const int*   ei   = (const int*)d_in[1];
    const float* ea   = (const float*)d_in[2];
    const float* m1w1 = (const float*)d_in[3];
    const float* m1b1 = (const float*)d_in[4];
    const float* m1w2 = (const float*)d_in[5];
    const float* m1b2 = (const float*)d_in[6];
    const float* m1w3 = (const float*)d_in[7];
    const float* m1b3 = (const float*)d_in[8];
    const float* m2w1 = (const float*)d_in[9];
    const float* m2b1 = (const float*)d_in[10];
    const float* m2w2 = (const float*)d_in[11];
    const float* m2b2 = (const float*)d_in[12];
    const float* ow1  = (const float*)d_in[13];
    const float* ob1  = (const float*)d_in[14];
    const float* ow2  = (const float*)d_in[15];
    const float* ob2  = (const float*)d_in[16];
    float* out = (float*)d_out;

    float* hidden   = (float*)d_ws;            // NN*8
    float* msg_base = hidden + (size_t)NN * 8; // NN
    float* agg      = msg_base + NN;           // NN

    dim3 blk(256);
    int nodeBlocks = (NN + 255) / 256;
    int edgeBlocks = (EE / 4 + 255) / 256;

    init_kernel<<<nodeBlocks, blk, 0, stream>>>(x, m1w1, m1b1, m1w2, m1b2, m1w3, m1b3,
                                                hidden, msg_base, agg);
    for (int t = 0; t < TT; ++t) {
        edge_kernel<<<edgeBlocks, blk, 0, stream>>>(ei, ea, msg_base, agg, t);
        node_kernel<<<nodeBlocks, blk, 0, stream>>>(x,
                                                    m1w1, m1b1, m1w2, m1b2, m1w3, m1b3,
                                                    m2w1, m2b1, m2w2, m2b2,
                                                    ow1, ob1, ow2, ob2,
                                                    hidden, msg_base, agg, out, t);
    }
}